// Round 6
// baseline (347.435 us; speedup 1.0000x reference)
//
#include <hip/hip_runtime.h>

// out[t,c] = bias[c] + sum_{k=0..99} w_norm[k,c] * x[t+k-99, c]   (x zero-padded t<0)
// T=16384, NC=2048, FW=100, all float32.
// Channel-major LDS ring (ds_read_b128) for x AND weights (both strides proven
// conflict-free in R5: 0 bank conflicts). Weight prep is cooperative (no big
// per-thread array). Allocator pinned at 3 waves/EU so nothing spills (R5 bug:
// launch_bounds min-only -> compiler chose 6 waves/EU, 84 VGPR, HBM scratch).

#define T_TOT 16384
#define NCH   2048
#define FW    100
#define CB    32          // channels per block
#define TB    128         // time steps per chunk
#define NTHR  256
#define ROWL  292         // ring row stride (floats): 256 + 36 pad
#define WROW  108         // weight row stride: 104 taps + 4 pad
#define NSEG  12          // 64 cgroups * 12 = 768 blocks = exactly 3/CU (LDS-limited)
#define NCHUNK_TOT (T_TOT / TB)   // 128

// One K-chunk of 8 taps (taps j = KI*8 .. KI*8+7 of the 104-tap shifted filter):
// load 8 new x floats into window slots NS..NS+7, 8 weights, 128 FMAs at phase PH.
#define KC_STEP(KI, PH, NS) do {                                                \
    int ro_ = (base0 + (KI)*8 + 16) & 255;                                      \
    float4 n0_ = *(const float4*)(rrow + ro_);                                  \
    float4 n1_ = *(const float4*)(rrow + ro_ + 4);                              \
    float4 w0_ = *(const float4*)(wrow + (KI)*8);                               \
    float4 w1_ = *(const float4*)(wrow + (KI)*8 + 4);                           \
    xw[(NS)+0]=n0_.x; xw[(NS)+1]=n0_.y; xw[(NS)+2]=n0_.z; xw[(NS)+3]=n0_.w;     \
    xw[(NS)+4]=n1_.x; xw[(NS)+5]=n1_.y; xw[(NS)+6]=n1_.z; xw[(NS)+7]=n1_.w;     \
    float wk_[8];                                                               \
    wk_[0]=w0_.x; wk_[1]=w0_.y; wk_[2]=w0_.z; wk_[3]=w0_.w;                     \
    wk_[4]=w1_.x; wk_[5]=w1_.y; wk_[6]=w1_.z; wk_[7]=w1_.w;                     \
    _Pragma("unroll")                                                           \
    for (int u_ = 0; u_ < 8; ++u_) {                                            \
      _Pragma("unroll")                                                         \
      for (int i_ = 0; i_ < 16; ++i_)                                           \
        acc[i_] = fmaf(wk_[u_], xw[((PH) + u_ + i_) % 24], acc[i_]);            \
    }                                                                           \
} while (0)

__global__ __launch_bounds__(NTHR)
__attribute__((amdgpu_waves_per_eu(3, 3)))
void catent_fir(const float* __restrict__ x,
                const float* __restrict__ wraw,
                const float* __restrict__ bias,
                float* __restrict__ out) {
    __shared__ __align__(16) float ring[CB * ROWL];   // 37376 B, ring[c*ROWL + (t&255)]
    __shared__ __align__(16) float wl[CB * WROW];     // 13824 B, wl[c*WROW + j], j=0..103

    const int tid   = threadIdx.x;
    const int cgrp  = blockIdx.x & 63;
    const int sidx  = blockIdx.x >> 6;          // 0..NSEG-1
    const int cbase = cgrp * CB;

    const int ch0 = (sidx * NCHUNK_TOT) / NSEG;
    const int ch1 = ((sidx + 1) * NCHUNK_TOT) / NSEG;
    const int tseg0 = ch0 * TB;

    const int c = tid & 31;
    const int g = tid >> 5;              // 0..7 time groups / tap-slice owners
    const int j0 = g * 13;               // this thread's 13-tap slice

    // ---- stage 1: relu(w) -> wl, cooperative (13 taps per thread, no reg array) ----
    // layout: w'[0]=0, w'[j]=relu(w[j-1][c]) for j=1..100, w'[101..107]=0
    {
        float* wr = &wl[c * WROW];
        #pragma unroll
        for (int jj = 0; jj < 13; ++jj) {
            int j = j0 + jj;
            float v = 0.0f;
            if (j >= 1 && j <= FW)
                v = fmaxf(wraw[(size_t)(j - 1) * NCH + cbase + c], 0.0f);
            wr[j] = v;
        }
        if (g == 7) { wr[104] = 0.0f; wr[105] = 0.0f; wr[106] = 0.0f; wr[107] = 0.0f; }
    }
    __syncthreads();

    // ---- stage 2: every thread computes its channel's L2 scale (identical order
    //      across the 8 g-threads -> bitwise-identical scl; reads only) ----
    float scl;
    {
        const float* wr = &wl[c * WROW];
        float4 s4 = make_float4(0.f, 0.f, 0.f, 0.f);
        #pragma unroll
        for (int q = 0; q < 27; ++q) {
            float4 v = *(const float4*)(wr + q * 4);
            s4.x = fmaf(v.x, v.x, s4.x); s4.y = fmaf(v.y, v.y, s4.y);
            s4.z = fmaf(v.z, v.z, s4.z); s4.w = fmaf(v.w, v.w, s4.w);
        }
        float s = (s4.x + s4.y) + (s4.z + s4.w);
        scl = rsqrtf(fmaxf(s, 1e-12f));
    }
    __syncthreads();

    // ---- stage 3: scale own slice; stage 4: x prologue (independent LDS) ----
    {
        float* wr = &wl[c * WROW];
        #pragma unroll
        for (int jj = 0; jj < 13; ++jj) wr[j0 + jj] *= scl;
    }
    {
        float* rw = &ring[c * ROWL];
        for (int p = 0; p < 2; ++p) {
            int tbase = tseg0 - TB + p * TB + g * 16;
            float v[16];
            #pragma unroll
            for (int j = 0; j < 16; ++j) {
                int t = tbase + j;
                v[j] = (t >= 0) ? x[(size_t)t * NCH + cbase + c] : 0.0f;
            }
            int rm = tbase & 255;
            #pragma unroll
            for (int q = 0; q < 4; ++q)
                *(float4*)(rw + rm + q * 4) = make_float4(v[q*4], v[q*4+1], v[q*4+2], v[q*4+3]);
            if (rm < 32) {
                #pragma unroll
                for (int q = 0; q < 4; ++q)
                    *(float4*)(rw + 256 + rm + q * 4) = make_float4(v[q*4], v[q*4+1], v[q*4+2], v[q*4+3]);
            }
        }
    }
    __syncthreads();

    const float biasr = bias[cbase + c];
    const float* rrow = &ring[c * ROWL];
    const float* wrow = &wl[c * WROW];
    float* rwr = &ring[c * ROWL];

    for (int ch = ch0; ch < ch1; ++ch) {
        const int t0 = ch * TB;
        const bool do_stage = (ch + 1 < ch1);

        // T14: issue next-chunk global loads early; ds_write after the drain barrier
        float stv[16];
        if (do_stage) {
            const size_t gb = (size_t)(t0 + TB + g * 16) * NCH + cbase + c;
            #pragma unroll
            for (int j = 0; j < 16; ++j) stv[j] = x[gb + (size_t)j * NCH];
        }

        float acc[16];
        #pragma unroll
        for (int i = 0; i < 16; ++i) acc[i] = biasr;

        float xw[24];
        const int base0 = t0 + g * 16 - 100;     // multiple of 4 => 16B-aligned ring reads

        // kc = 0: fill window x[base0 .. base0+23], taps j=0..7 (w'[0]=0)
        {
            int ro = base0 & 255;
            #pragma unroll
            for (int q = 0; q < 6; ++q) {
                float4 v = *(const float4*)(rrow + ro + q * 4);
                xw[q*4+0] = v.x; xw[q*4+1] = v.y; xw[q*4+2] = v.z; xw[q*4+3] = v.w;
            }
            float4 w0 = *(const float4*)(wrow);
            float4 w1 = *(const float4*)(wrow + 4);
            float wk[8];
            wk[0]=w0.x; wk[1]=w0.y; wk[2]=w0.z; wk[3]=w0.w;
            wk[4]=w1.x; wk[5]=w1.y; wk[6]=w1.z; wk[7]=w1.w;
            #pragma unroll
            for (int u = 0; u < 8; ++u) {
                #pragma unroll
                for (int i = 0; i < 16; ++i)
                    acc[i] = fmaf(wk[u], xw[(u + i) % 24], acc[i]);
            }
        }

        // kc = 1..12: slide by 8 (register rotation, phase period 3).
        // Taps 101..103 are zero; their (stale but finite) x reads contribute 0.
        KC_STEP(1,  8, 0);
        KC_STEP(2, 16, 8);
        KC_STEP(3,  0, 16);
        KC_STEP(4,  8, 0);
        KC_STEP(5, 16, 8);
        KC_STEP(6,  0, 16);
        KC_STEP(7,  8, 0);
        KC_STEP(8, 16, 8);
        KC_STEP(9,  0, 16);
        KC_STEP(10, 8, 0);
        KC_STEP(11,16, 8);
        KC_STEP(12, 0, 16);

        __syncthreads();   // all ring reads of this chunk done

        if (do_stage) {
            int rm = (t0 + TB + g * 16) & 255;
            #pragma unroll
            for (int q = 0; q < 4; ++q)
                *(float4*)(rwr + rm + q * 4) = make_float4(stv[q*4], stv[q*4+1], stv[q*4+2], stv[q*4+3]);
            if (rm < 32) {
                #pragma unroll
                for (int q = 0; q < 4; ++q)
                    *(float4*)(rwr + 256 + rm + q * 4) = make_float4(stv[q*4], stv[q*4+1], stv[q*4+2], stv[q*4+3]);
            }
        }
        __syncthreads();   // staged rows visible for next chunk

        // stores last: they drain during the next chunk's compute, not at a barrier
        {
            size_t ob = (size_t)(t0 + g * 16) * NCH + cbase + c;
            #pragma unroll
            for (int i = 0; i < 16; ++i) out[ob + (size_t)i * NCH] = acc[i];
        }
    }
}

extern "C" void kernel_launch(void* const* d_in, const int* in_sizes, int n_in,
                              void* d_out, int out_size, void* d_ws, size_t ws_size,
                              hipStream_t stream) {
    const float* x    = (const float*)d_in[0];   // [T, NC]
    const float* wraw = (const float*)d_in[1];   // [FW, NC]
    const float* bias = (const float*)d_in[2];   // [1, NC]
    float* out = (float*)d_out;                  // [T, NC]

    dim3 grid(64 * NSEG);   // 768 blocks = exactly 3/CU
    dim3 block(NTHR);
    catent_fir<<<grid, block, 0, stream>>>(x, wraw, bias, out);
}

// Round 7
// 134.574 us; speedup vs baseline: 2.5817x; 2.5817x over previous
//
#include <hip/hip_runtime.h>

// out[t,c] = bias[c] + sum_{k=0..99} w_norm[k,c] * x[t+k-99, c]   (x zero-padded t<0)
// T=16384, NC=2048, FW=100, all float32.
// Channel-major LDS ring (ds_read_b128) for x AND weights (strides 292/108:
// proven conflict-free R4/R5). Cooperative weight prep (no big per-thread array).
// Register policy: __launch_bounds__(256,2) is the ONLY pin that empirically
// yields VGPR=128 + zero scratch HBM traffic (R4). (256,3)/waves_per_eu(3,3)
// made the allocator target 6 waves/EU -> 84 VGPR -> 500+ MB spill traffic (R5/R6).

#define T_TOT 16384
#define NCH   2048
#define FW    100
#define CB    32          // channels per block
#define TB    128         // time steps per chunk
#define NTHR  256
#define ROWL  292         // ring row stride (floats): 256 + 36 pad
#define WROW  108         // weight row stride: 104 taps + 4 pad
#define NSEG  12          // 64 cgroups * 12 = 768 blocks = 3/CU (LDS-limited)
#define NCHUNK_TOT (T_TOT / TB)   // 128

// One K-chunk of 8 taps (taps j = KI*8 .. KI*8+7 of the 104-tap shifted filter):
// load 8 new x floats into window slots NS..NS+7, 8 weights, 128 FMAs at phase PH.
#define KC_STEP(KI, PH, NS) do {                                                \
    int ro_ = (base0 + (KI)*8 + 16) & 255;                                      \
    float4 n0_ = *(const float4*)(rrow + ro_);                                  \
    float4 n1_ = *(const float4*)(rrow + ro_ + 4);                              \
    float4 w0_ = *(const float4*)(wrow + (KI)*8);                               \
    float4 w1_ = *(const float4*)(wrow + (KI)*8 + 4);                           \
    xw[(NS)+0]=n0_.x; xw[(NS)+1]=n0_.y; xw[(NS)+2]=n0_.z; xw[(NS)+3]=n0_.w;     \
    xw[(NS)+4]=n1_.x; xw[(NS)+5]=n1_.y; xw[(NS)+6]=n1_.z; xw[(NS)+7]=n1_.w;     \
    float wk_[8];                                                               \
    wk_[0]=w0_.x; wk_[1]=w0_.y; wk_[2]=w0_.z; wk_[3]=w0_.w;                     \
    wk_[4]=w1_.x; wk_[5]=w1_.y; wk_[6]=w1_.z; wk_[7]=w1_.w;                     \
    _Pragma("unroll")                                                           \
    for (int u_ = 0; u_ < 8; ++u_) {                                            \
      _Pragma("unroll")                                                         \
      for (int i_ = 0; i_ < 16; ++i_)                                           \
        acc[i_] = fmaf(wk_[u_], xw[((PH) + u_ + i_) % 24], acc[i_]);            \
    }                                                                           \
} while (0)

__global__ __launch_bounds__(NTHR, 2)
void catent_fir(const float* __restrict__ x,
                const float* __restrict__ wraw,
                const float* __restrict__ bias,
                float* __restrict__ out) {
    __shared__ __align__(16) float ring[CB * ROWL];   // 37376 B, ring[c*ROWL + (t&255)]
    __shared__ __align__(16) float wl[CB * WROW];     // 13824 B, wl[c*WROW + j], j=0..103

    const int tid   = threadIdx.x;
    const int cgrp  = blockIdx.x & 63;
    const int sidx  = blockIdx.x >> 6;          // 0..NSEG-1
    const int cbase = cgrp * CB;

    const int ch0 = (sidx * NCHUNK_TOT) / NSEG;
    const int ch1 = ((sidx + 1) * NCHUNK_TOT) / NSEG;
    const int tseg0 = ch0 * TB;

    const int c = tid & 31;
    const int g = tid >> 5;              // 0..7 time groups / tap-slice owners
    const int j0 = g * 13;               // this thread's 13-tap slice

    // ---- stage 1: relu(w) -> wl, cooperative (13 taps per thread, no reg array) ----
    // layout: w'[0]=0, w'[j]=relu(w[j-1][c]) for j=1..100, w'[101..107]=0
    {
        float* wr = &wl[c * WROW];
        #pragma unroll
        for (int jj = 0; jj < 13; ++jj) {
            int j = j0 + jj;
            float v = 0.0f;
            if (j >= 1 && j <= FW)
                v = fmaxf(wraw[(size_t)(j - 1) * NCH + cbase + c], 0.0f);
            wr[j] = v;
        }
        if (g == 7) { wr[104] = 0.0f; wr[105] = 0.0f; wr[106] = 0.0f; wr[107] = 0.0f; }
    }
    __syncthreads();

    // ---- stage 2: every thread computes its channel's L2 scale (identical order
    //      across the 8 g-threads -> bitwise-identical scl; reads only) ----
    float scl;
    {
        const float* wr = &wl[c * WROW];
        float4 s4 = make_float4(0.f, 0.f, 0.f, 0.f);
        #pragma unroll
        for (int q = 0; q < 27; ++q) {
            float4 v = *(const float4*)(wr + q * 4);
            s4.x = fmaf(v.x, v.x, s4.x); s4.y = fmaf(v.y, v.y, s4.y);
            s4.z = fmaf(v.z, v.z, s4.z); s4.w = fmaf(v.w, v.w, s4.w);
        }
        float s = (s4.x + s4.y) + (s4.z + s4.w);
        scl = rsqrtf(fmaxf(s, 1e-12f));
    }
    __syncthreads();

    // ---- stage 3: scale own slice; stage 4: x prologue (independent LDS) ----
    {
        float* wr = &wl[c * WROW];
        #pragma unroll
        for (int jj = 0; jj < 13; ++jj) wr[j0 + jj] *= scl;
    }
    {
        float* rw = &ring[c * ROWL];
        for (int p = 0; p < 2; ++p) {
            int tbase = tseg0 - TB + p * TB + g * 16;
            float v[16];
            #pragma unroll
            for (int j = 0; j < 16; ++j) {
                int t = tbase + j;
                v[j] = (t >= 0) ? x[(size_t)t * NCH + cbase + c] : 0.0f;
            }
            int rm = tbase & 255;
            #pragma unroll
            for (int q = 0; q < 4; ++q)
                *(float4*)(rw + rm + q * 4) = make_float4(v[q*4], v[q*4+1], v[q*4+2], v[q*4+3]);
            if (rm < 32) {
                #pragma unroll
                for (int q = 0; q < 4; ++q)
                    *(float4*)(rw + 256 + rm + q * 4) = make_float4(v[q*4], v[q*4+1], v[q*4+2], v[q*4+3]);
            }
        }
    }
    __syncthreads();

    const float biasr = bias[cbase + c];
    const float* rrow = &ring[c * ROWL];
    const float* wrow = &wl[c * WROW];
    float* rwr = &ring[c * ROWL];

    for (int ch = ch0; ch < ch1; ++ch) {
        const int t0 = ch * TB;
        const bool do_stage = (ch + 1 < ch1);

        // T14: issue next-chunk global loads early; ds_write after the drain barrier
        float stv[16];
        if (do_stage) {
            const size_t gb = (size_t)(t0 + TB + g * 16) * NCH + cbase + c;
            #pragma unroll
            for (int j = 0; j < 16; ++j) stv[j] = x[gb + (size_t)j * NCH];
        }

        float acc[16];
        #pragma unroll
        for (int i = 0; i < 16; ++i) acc[i] = biasr;

        float xw[24];
        const int base0 = t0 + g * 16 - 100;     // multiple of 4 => 16B-aligned ring reads

        // kc = 0: fill window x[base0 .. base0+23], taps j=0..7 (w'[0]=0)
        {
            int ro = base0 & 255;
            #pragma unroll
            for (int q = 0; q < 6; ++q) {
                float4 v = *(const float4*)(rrow + ro + q * 4);
                xw[q*4+0] = v.x; xw[q*4+1] = v.y; xw[q*4+2] = v.z; xw[q*4+3] = v.w;
            }
            float4 w0 = *(const float4*)(wrow);
            float4 w1 = *(const float4*)(wrow + 4);
            float wk[8];
            wk[0]=w0.x; wk[1]=w0.y; wk[2]=w0.z; wk[3]=w0.w;
            wk[4]=w1.x; wk[5]=w1.y; wk[6]=w1.z; wk[7]=w1.w;
            #pragma unroll
            for (int u = 0; u < 8; ++u) {
                #pragma unroll
                for (int i = 0; i < 16; ++i)
                    acc[i] = fmaf(wk[u], xw[(u + i) % 24], acc[i]);
            }
        }

        // kc = 1..12: slide by 8 (register rotation, phase period 3).
        // Taps 101..103 are zero; their (stale but finite) x reads contribute 0.
        KC_STEP(1,  8, 0);
        KC_STEP(2, 16, 8);
        KC_STEP(3,  0, 16);
        KC_STEP(4,  8, 0);
        KC_STEP(5, 16, 8);
        KC_STEP(6,  0, 16);
        KC_STEP(7,  8, 0);
        KC_STEP(8, 16, 8);
        KC_STEP(9,  0, 16);
        KC_STEP(10, 8, 0);
        KC_STEP(11,16, 8);
        KC_STEP(12, 0, 16);

        __syncthreads();   // all ring reads of this chunk done

        if (do_stage) {
            int rm = (t0 + TB + g * 16) & 255;
            #pragma unroll
            for (int q = 0; q < 4; ++q)
                *(float4*)(rwr + rm + q * 4) = make_float4(stv[q*4], stv[q*4+1], stv[q*4+2], stv[q*4+3]);
            if (rm < 32) {
                #pragma unroll
                for (int q = 0; q < 4; ++q)
                    *(float4*)(rwr + 256 + rm + q * 4) = make_float4(stv[q*4], stv[q*4+1], stv[q*4+2], stv[q*4+3]);
            }
        }
        __syncthreads();   // staged rows visible for next chunk

        // stores last: they drain during the next chunk's compute, not at a barrier
        {
            size_t ob = (size_t)(t0 + g * 16) * NCH + cbase + c;
            #pragma unroll
            for (int i = 0; i < 16; ++i) out[ob + (size_t)i * NCH] = acc[i];
        }
    }
}

extern "C" void kernel_launch(void* const* d_in, const int* in_sizes, int n_in,
                              void* d_out, int out_size, void* d_ws, size_t ws_size,
                              hipStream_t stream) {
    const float* x    = (const float*)d_in[0];   // [T, NC]
    const float* wraw = (const float*)d_in[1];   // [FW, NC]
    const float* bias = (const float*)d_in[2];   // [1, NC]
    float* out = (float*)d_out;                  // [T, NC]

    dim3 grid(64 * NSEG);   // 768 blocks = 3/CU
    dim3 block(NTHR);
    catent_fir<<<grid, block, 0, stream>>>(x, wraw, bias, out);
}

// Round 8
// 120.326 us; speedup vs baseline: 2.8875x; 1.1184x over previous
//
#include <hip/hip_runtime.h>

// out[t,c] = bias[c] + sum_{k=0..99} w_norm[k,c] * x[t+k-99, c]   (x zero-padded t<0)
// T=16384, NC=2048, FW=100, all float32.
// Channel-major LDS ring (ds_read_b128) for x AND weights (strides 292/108:
// conflict-free, proven R4/R5). Cooperative weight prep (no big per-thread array).
// Register policy: __launch_bounds__(256,2) -> VGPR=128, no HBM scratch (R4/R7).
// Grid policy: NSEG=8 -> 512 blocks = exactly 2 blocks/CU resident, perfectly
// balanced (R7 lesson: at VGPR=128 residency is 2/CU; a 768-block grid ran as
// 1.5 rounds -> 33% tail waste, occupancy 16.6%, dur +27us).

#define T_TOT 16384
#define NCH   2048
#define FW    100
#define CB    32          // channels per block
#define TB    128         // time steps per chunk
#define NTHR  256
#define ROWL  292         // ring row stride (floats): 256 + 36 pad
#define WROW  108         // weight row stride: 104 taps + 4 pad
#define NSEG  8           // 64 cgroups * 8 = 512 blocks = exactly 2/CU
#define NCHUNK (T_TOT / TB / NSEG)   // 16 chunks per segment

// One K-chunk of 8 taps (taps j = KI*8 .. KI*8+7 of the 104-tap shifted filter):
// load 8 new x floats into window slots NS..NS+7, 8 weights, 128 FMAs at phase PH.
#define KC_STEP(KI, PH, NS) do {                                                \
    int ro_ = (base0 + (KI)*8 + 16) & 255;                                      \
    float4 n0_ = *(const float4*)(rrow + ro_);                                  \
    float4 n1_ = *(const float4*)(rrow + ro_ + 4);                              \
    float4 w0_ = *(const float4*)(wrow + (KI)*8);                               \
    float4 w1_ = *(const float4*)(wrow + (KI)*8 + 4);                           \
    xw[(NS)+0]=n0_.x; xw[(NS)+1]=n0_.y; xw[(NS)+2]=n0_.z; xw[(NS)+3]=n0_.w;     \
    xw[(NS)+4]=n1_.x; xw[(NS)+5]=n1_.y; xw[(NS)+6]=n1_.z; xw[(NS)+7]=n1_.w;     \
    float wk_[8];                                                               \
    wk_[0]=w0_.x; wk_[1]=w0_.y; wk_[2]=w0_.z; wk_[3]=w0_.w;                     \
    wk_[4]=w1_.x; wk_[5]=w1_.y; wk_[6]=w1_.z; wk_[7]=w1_.w;                     \
    _Pragma("unroll")                                                           \
    for (int u_ = 0; u_ < 8; ++u_) {                                            \
      _Pragma("unroll")                                                         \
      for (int i_ = 0; i_ < 16; ++i_)                                           \
        acc[i_] = fmaf(wk_[u_], xw[((PH) + u_ + i_) % 24], acc[i_]);            \
    }                                                                           \
} while (0)

__global__ __launch_bounds__(NTHR, 2)
void catent_fir(const float* __restrict__ x,
                const float* __restrict__ wraw,
                const float* __restrict__ bias,
                float* __restrict__ out) {
    __shared__ __align__(16) float ring[CB * ROWL];   // 37376 B, ring[c*ROWL + (t&255)]
    __shared__ __align__(16) float wl[CB * WROW];     // 13824 B, wl[c*WROW + j], j=0..103

    const int tid   = threadIdx.x;
    const int cgrp  = blockIdx.x & 63;
    const int sidx  = blockIdx.x >> 6;          // 0..NSEG-1
    const int cbase = cgrp * CB;

    const int ch0 = sidx * NCHUNK;
    const int tseg0 = ch0 * TB;

    const int c = tid & 31;
    const int g = tid >> 5;              // 0..7 time groups / tap-slice owners
    const int j0 = g * 13;               // this thread's 13-tap slice

    // ---- stage 1: relu(w) -> wl, cooperative (13 taps per thread, no reg array) ----
    // layout: w'[0]=0, w'[j]=relu(w[j-1][c]) for j=1..100, w'[101..107]=0
    {
        float* wr = &wl[c * WROW];
        #pragma unroll
        for (int jj = 0; jj < 13; ++jj) {
            int j = j0 + jj;
            float v = 0.0f;
            if (j >= 1 && j <= FW)
                v = fmaxf(wraw[(size_t)(j - 1) * NCH + cbase + c], 0.0f);
            wr[j] = v;
        }
        if (g == 7) { wr[104] = 0.0f; wr[105] = 0.0f; wr[106] = 0.0f; wr[107] = 0.0f; }
    }
    __syncthreads();

    // ---- stage 2: every thread computes its channel's L2 scale (identical order
    //      across the 8 g-threads -> bitwise-identical scl; reads only) ----
    float scl;
    {
        const float* wr = &wl[c * WROW];
        float4 s4 = make_float4(0.f, 0.f, 0.f, 0.f);
        #pragma unroll
        for (int q = 0; q < 27; ++q) {
            float4 v = *(const float4*)(wr + q * 4);
            s4.x = fmaf(v.x, v.x, s4.x); s4.y = fmaf(v.y, v.y, s4.y);
            s4.z = fmaf(v.z, v.z, s4.z); s4.w = fmaf(v.w, v.w, s4.w);
        }
        float s = (s4.x + s4.y) + (s4.z + s4.w);
        scl = rsqrtf(fmaxf(s, 1e-12f));
    }
    __syncthreads();

    // ---- stage 3: scale own slice; stage 4: x prologue (independent LDS) ----
    {
        float* wr = &wl[c * WROW];
        #pragma unroll
        for (int jj = 0; jj < 13; ++jj) wr[j0 + jj] *= scl;
    }
    {
        float* rw = &ring[c * ROWL];
        for (int p = 0; p < 2; ++p) {
            int tbase = tseg0 - TB + p * TB + g * 16;
            float v[16];
            #pragma unroll
            for (int j = 0; j < 16; ++j) {
                int t = tbase + j;
                v[j] = (t >= 0) ? x[(size_t)t * NCH + cbase + c] : 0.0f;
            }
            int rm = tbase & 255;
            #pragma unroll
            for (int q = 0; q < 4; ++q)
                *(float4*)(rw + rm + q * 4) = make_float4(v[q*4], v[q*4+1], v[q*4+2], v[q*4+3]);
            if (rm < 32) {
                #pragma unroll
                for (int q = 0; q < 4; ++q)
                    *(float4*)(rw + 256 + rm + q * 4) = make_float4(v[q*4], v[q*4+1], v[q*4+2], v[q*4+3]);
            }
        }
    }
    __syncthreads();

    const float biasr = bias[cbase + c];
    const float* rrow = &ring[c * ROWL];
    const float* wrow = &wl[c * WROW];
    float* rwr = &ring[c * ROWL];

    for (int ch = ch0; ch < ch0 + NCHUNK; ++ch) {
        const int t0 = ch * TB;
        const bool do_stage = (ch + 1 < ch0 + NCHUNK);

        // T14: issue next-chunk global loads early; ds_write after the drain barrier
        float stv[16];
        if (do_stage) {
            const size_t gb = (size_t)(t0 + TB + g * 16) * NCH + cbase + c;
            #pragma unroll
            for (int j = 0; j < 16; ++j) stv[j] = x[gb + (size_t)j * NCH];
        }

        float acc[16];
        #pragma unroll
        for (int i = 0; i < 16; ++i) acc[i] = biasr;

        float xw[24];
        const int base0 = t0 + g * 16 - 100;     // multiple of 4 => 16B-aligned ring reads

        // kc = 0: fill window x[base0 .. base0+23], taps j=0..7 (w'[0]=0)
        {
            int ro = base0 & 255;
            #pragma unroll
            for (int q = 0; q < 6; ++q) {
                float4 v = *(const float4*)(rrow + ro + q * 4);
                xw[q*4+0] = v.x; xw[q*4+1] = v.y; xw[q*4+2] = v.z; xw[q*4+3] = v.w;
            }
            float4 w0 = *(const float4*)(wrow);
            float4 w1 = *(const float4*)(wrow + 4);
            float wk[8];
            wk[0]=w0.x; wk[1]=w0.y; wk[2]=w0.z; wk[3]=w0.w;
            wk[4]=w1.x; wk[5]=w1.y; wk[6]=w1.z; wk[7]=w1.w;
            #pragma unroll
            for (int u = 0; u < 8; ++u) {
                #pragma unroll
                for (int i = 0; i < 16; ++i)
                    acc[i] = fmaf(wk[u], xw[(u + i) % 24], acc[i]);
            }
        }

        // kc = 1..12: slide by 8 (register rotation, phase period 3).
        // Taps 101..103 are zero; their (stale but finite) x reads contribute 0.
        KC_STEP(1,  8, 0);
        KC_STEP(2, 16, 8);
        KC_STEP(3,  0, 16);
        KC_STEP(4,  8, 0);
        KC_STEP(5, 16, 8);
        KC_STEP(6,  0, 16);
        KC_STEP(7,  8, 0);
        KC_STEP(8, 16, 8);
        KC_STEP(9,  0, 16);
        KC_STEP(10, 8, 0);
        KC_STEP(11,16, 8);
        KC_STEP(12, 0, 16);

        __syncthreads();   // all ring reads of this chunk done

        if (do_stage) {
            int rm = (t0 + TB + g * 16) & 255;
            #pragma unroll
            for (int q = 0; q < 4; ++q)
                *(float4*)(rwr + rm + q * 4) = make_float4(stv[q*4], stv[q*4+1], stv[q*4+2], stv[q*4+3]);
            if (rm < 32) {
                #pragma unroll
                for (int q = 0; q < 4; ++q)
                    *(float4*)(rwr + 256 + rm + q * 4) = make_float4(stv[q*4], stv[q*4+1], stv[q*4+2], stv[q*4+3]);
            }
        }
        __syncthreads();   // staged rows visible for next chunk

        // stores last: they drain during the next chunk's compute, not at a barrier
        {
            size_t ob = (size_t)(t0 + g * 16) * NCH + cbase + c;
            #pragma unroll
            for (int i = 0; i < 16; ++i) out[ob + (size_t)i * NCH] = acc[i];
        }
    }
}

extern "C" void kernel_launch(void* const* d_in, const int* in_sizes, int n_in,
                              void* d_out, int out_size, void* d_ws, size_t ws_size,
                              hipStream_t stream) {
    const float* x    = (const float*)d_in[0];   // [T, NC]
    const float* wraw = (const float*)d_in[1];   // [FW, NC]
    const float* bias = (const float*)d_in[2];   // [1, NC]
    float* out = (float*)d_out;                  // [T, NC]

    dim3 grid(64 * NSEG);   // 512 blocks = exactly 2/CU
    dim3 block(NTHR);
    catent_fir<<<grid, block, 0, stream>>>(x, wraw, bias, out);
}

// Round 9
// 118.474 us; speedup vs baseline: 2.9326x; 1.0156x over previous
//
#include <hip/hip_runtime.h>

// out[t,c] = bias[c] + sum_{k=0..99} w_norm[k,c] * x[t+k-99, c]   (x zero-padded t<0)
// T=16384, NC=2048, FW=100, all float32.
//
// R9 design:
//  - x in channel-major LDS ring (ds_read_b128, stride 292: conflict-free, R4/R5/R8).
//  - Weights: RAW relu'd values read from global (L2-resident, VMEM pipe) inside
//    the loop; L2-normalization folded into epilogue scale (out = bias + scl*acc).
//    -> no weight LDS, LDS/block = 37.4KB, LDS-pipe traffic nearly halved.
//  - Occupancy: empirical rule from R4-R8: VGPR<=85 & LDS<=~42KB -> 3 blocks/CU.
//    launch_bounds(256,6) caps VGPR at 85; live set ~70 (no stv, no wreg array).
//    Grid 768 = exactly 3/CU.

#define T_TOT 16384
#define NCH   2048
#define FW    100
#define CB    32          // channels per block
#define TB    128         // time steps per chunk
#define NTHR  256
#define ROWL  292         // ring row stride (floats): 256 + 36 pad (mirror [0,32)->[256,288))
#define NSEG  12          // 64 cgroups * 12 = 768 blocks = 3/CU
#define NCHUNK_TOT (T_TOT / TB)   // 128

// Steps KI=1..11: taps j=KI*8..KI*8+7 (w'[j] = relu(wraw[j-1])), 8 w loads rows KI*8-1..+6,
// 8 new x into xw[NS..NS+7], 128 FMAs at phase PH.
#define KC_STEP(KI, PH, NS) do {                                                \
    int ro_ = (base0 + (KI)*8 + 16) & 255;                                      \
    float4 n0_ = *(const float4*)(rrow + ro_);                                  \
    float4 n1_ = *(const float4*)(rrow + ro_ + 4);                              \
    float wk_[8];                                                               \
    _Pragma("unroll")                                                           \
    for (int u_ = 0; u_ < 8; ++u_)                                              \
        wk_[u_] = fmaxf(wcol[(size_t)((KI)*8 - 1 + u_) * NCH], 0.0f);           \
    xw[(NS)+0]=n0_.x; xw[(NS)+1]=n0_.y; xw[(NS)+2]=n0_.z; xw[(NS)+3]=n0_.w;     \
    xw[(NS)+4]=n1_.x; xw[(NS)+5]=n1_.y; xw[(NS)+6]=n1_.z; xw[(NS)+7]=n1_.w;     \
    _Pragma("unroll")                                                           \
    for (int u_ = 0; u_ < 8; ++u_) {                                            \
      _Pragma("unroll")                                                         \
      for (int i_ = 0; i_ < 16; ++i_)                                           \
        acc[i_] = fmaf(wk_[u_], xw[((PH) + u_ + i_) % 24], acc[i_]);            \
    }                                                                           \
} while (0)

__global__ __launch_bounds__(NTHR, 6)
void catent_fir(const float* __restrict__ x,
                const float* __restrict__ wraw,
                const float* __restrict__ bias,
                float* __restrict__ out) {
    __shared__ __align__(16) float ring[CB * ROWL];   // 37376 B

    const int tid   = threadIdx.x;
    const int cgrp  = blockIdx.x & 63;
    const int sidx  = blockIdx.x >> 6;          // 0..NSEG-1
    const int cbase = cgrp * CB;

    const int ch0 = (sidx * NCHUNK_TOT) / NSEG;
    const int ch1 = ((sidx + 1) * NCHUNK_TOT) / NSEG;
    const int tseg0 = ch0 * TB;

    const int c = tid & 31;
    const int g = tid >> 5;              // 0..7
    const float* wcol = wraw + cbase + c;

    // ---- prologue A: per-channel L2 scale via cooperative partial sums ----
    // thread (c,g) sums relu(w[g*13 .. g*13+12])^2 (clamped to <100)
    {
        float ps = 0.0f;
        #pragma unroll
        for (int jj = 0; jj < 13; ++jj) {
            int row = g * 13 + jj;
            if (row < FW) {
                float v = fmaxf(wcol[(size_t)row * NCH], 0.0f);
                ps = fmaf(v, v, ps);
            }
        }
        ring[c * ROWL + g] = ps;   // ring as scratch (overwritten by x prologue)
    }
    __syncthreads();
    float scl;
    {
        float4 p0 = *(const float4*)(&ring[c * ROWL]);
        float4 p1 = *(const float4*)(&ring[c * ROWL + 4]);
        float s = ((p0.x + p0.y) + (p0.z + p0.w)) + ((p1.x + p1.y) + (p1.z + p1.w));
        scl = rsqrtf(fmaxf(s, 1e-12f));
    }
    __syncthreads();

    // ---- prologue B: stage times [tseg0-128, tseg0+127]; mirror [0,32)->[256,288) ----
    {
        float* rw = &ring[c * ROWL];
        for (int p = 0; p < 2; ++p) {
            int tbase = tseg0 - TB + p * TB + g * 16;
            float v[16];
            #pragma unroll
            for (int j = 0; j < 16; ++j) {
                int t = tbase + j;
                v[j] = (t >= 0) ? x[(size_t)t * NCH + cbase + c] : 0.0f;
            }
            int rm = tbase & 255;
            #pragma unroll
            for (int q = 0; q < 4; ++q)
                *(float4*)(rw + rm + q * 4) = make_float4(v[q*4], v[q*4+1], v[q*4+2], v[q*4+3]);
            if (rm < 32) {
                #pragma unroll
                for (int q = 0; q < 4; ++q)
                    *(float4*)(rw + 256 + rm + q * 4) = make_float4(v[q*4], v[q*4+1], v[q*4+2], v[q*4+3]);
            }
        }
    }
    __syncthreads();

    const float biasr = bias[cbase + c];
    const float* rrow = &ring[c * ROWL];
    float* rwr = &ring[c * ROWL];

    for (int ch = ch0; ch < ch1; ++ch) {
        const int t0 = ch * TB;
        const bool do_stage = (ch + 1 < ch1);

        float acc[16];
        #pragma unroll
        for (int i = 0; i < 16; ++i) acc[i] = 0.0f;

        float xw[24];
        const int base0 = t0 + g * 16 - 100;     // multiple of 4 -> 16B-aligned ring reads

        // kc = 0: fill xw[0..23] = x[base0..base0+23]; taps j=1..7 (w'[0]=0 -> skip u=0)
        {
            int ro = base0 & 255;
            #pragma unroll
            for (int q = 0; q < 6; ++q) {
                float4 v = *(const float4*)(rrow + ro + q * 4);
                xw[q*4+0] = v.x; xw[q*4+1] = v.y; xw[q*4+2] = v.z; xw[q*4+3] = v.w;
            }
            float wk[8];
            wk[0] = 0.0f;
            #pragma unroll
            for (int u = 1; u < 8; ++u)
                wk[u] = fmaxf(wcol[(size_t)(u - 1) * NCH], 0.0f);
            #pragma unroll
            for (int u = 1; u < 8; ++u) {
                #pragma unroll
                for (int i = 0; i < 16; ++i)
                    acc[i] = fmaf(wk[u], xw[(u + i) % 24], acc[i]);
            }
        }

        // kc = 1..11: slide by 8 (register rotation, phase period 3)
        KC_STEP(1,  8, 0);
        KC_STEP(2, 16, 8);
        KC_STEP(3,  0, 16);
        KC_STEP(4,  8, 0);
        KC_STEP(5, 16, 8);
        KC_STEP(6,  0, 16);
        KC_STEP(7,  8, 0);
        KC_STEP(8, 16, 8);
        KC_STEP(9,  0, 16);
        KC_STEP(10, 8, 0);
        KC_STEP(11,16, 8);

        // kc = 12 (tail): taps j=96..100 (rows 95..99); j=101..103 are zero -> u=0..4 only
        {
            int ro = (base0 + 112) & 255;
            float4 n0 = *(const float4*)(rrow + ro);
            float4 n1 = *(const float4*)(rrow + ro + 4);
            float wk[5];
            #pragma unroll
            for (int u = 0; u < 5; ++u)
                wk[u] = fmaxf(wcol[(size_t)(95 + u) * NCH], 0.0f);
            xw[16]=n0.x; xw[17]=n0.y; xw[18]=n0.z; xw[19]=n0.w;
            xw[20]=n1.x; xw[21]=n1.y; xw[22]=n1.z; xw[23]=n1.w;
            #pragma unroll
            for (int u = 0; u < 5; ++u) {
                #pragma unroll
                for (int i = 0; i < 16; ++i)
                    acc[i] = fmaf(wk[u], xw[(u + i) % 24], acc[i]);
            }
        }

        __syncthreads();   // all ring reads of this chunk done

        if (do_stage) {    // stage next chunk: global -> regs -> LDS (between barriers)
            const int tb = t0 + TB + g * 16;
            const size_t gb = (size_t)tb * NCH + cbase + c;
            float sv[16];
            #pragma unroll
            for (int j = 0; j < 16; ++j) sv[j] = x[gb + (size_t)j * NCH];
            int rm = tb & 255;
            #pragma unroll
            for (int q = 0; q < 4; ++q)
                *(float4*)(rwr + rm + q * 4) = make_float4(sv[q*4], sv[q*4+1], sv[q*4+2], sv[q*4+3]);
            if (rm < 32) {
                #pragma unroll
                for (int q = 0; q < 4; ++q)
                    *(float4*)(rwr + 256 + rm + q * 4) = make_float4(sv[q*4], sv[q*4+1], sv[q*4+2], sv[q*4+3]);
            }
        }
        __syncthreads();   // staged rows visible for next chunk

        // epilogue: out = bias + scl*acc; stores drain under next chunk's compute
        {
            size_t ob = (size_t)(t0 + g * 16) * NCH + cbase + c;
            #pragma unroll
            for (int i = 0; i < 16; ++i) out[ob + (size_t)i * NCH] = fmaf(scl, acc[i], biasr);
        }
    }
}

extern "C" void kernel_launch(void* const* d_in, const int* in_sizes, int n_in,
                              void* d_out, int out_size, void* d_ws, size_t ws_size,
                              hipStream_t stream) {
    const float* x    = (const float*)d_in[0];   // [T, NC]
    const float* wraw = (const float*)d_in[1];   // [FW, NC]
    const float* bias = (const float*)d_in[2];   // [1, NC]
    float* out = (float*)d_out;                  // [T, NC]

    dim3 grid(64 * NSEG);   // 768 blocks = 3/CU
    dim3 block(NTHR);
    catent_fir<<<grid, block, 0, stream>>>(x, wraw, bias, out);
}